// Round 8
// baseline (284.662 us; speedup 1.0000x reference)
//
#include <hip/hip_runtime.h>
#include <stdint.h>
#include <stddef.h>

// MASLoRALinear via concatenation identity:
//   hg[b,t,e*16+r] = SCALING * w[b,e] * (x @ As^T)[b,t,e,r]      (gate baked in)
//   out = [x_bf16 | hg] @ [W_base | Bcat]^T + b_base
// Round 11: main_gemm -> 3-buffer / ONE-barrier-per-K-tile pipeline. Diagnosed
// residue (R5/R6/R7 all ~5100cy/tile vs ~1800cy overlapped bound, conflicts 0,
// vmcnt satisfied): 2 barriers/tile + monolithic all-wave phases. 3 LDS
// buffers (t%3 read, (t+2)%3 staged = buffer last read at t-1) eliminate the
// mid-tile overwrite barrier -> 18 barriers total. Per tile: vmcnt(6); BAR;
// GLL t+2; 16 ds_reads in 4 pinned groups; lgkm(8)->8 MFMA; lgkm(4)->8;
// lgkm(0)->16. BM=128 BN=256 (144 KB LDS), 8 waves -> wave 64x64, 752 blocks
// = 2.94 rounds (98% makespan), bijective XCD-chunk, nt-fastest (A-panel L2
// reuse). XOR-8 LDS (0 conflicts, R5-R7 verified). cvt/h_gemm/prep unchanged.

#define B_ 16
#define T_ 1500
#define C_ 1024
#define O_ 1024
#define E_ 8
#define R_ 16
#define ER 128     // E*R
#define KK 1152    // C_ + ER
#define BT 24000   // B_*T_
#define NKT 18     // KK / 64 K-tiles
#define SCALING 2.0f

typedef __bf16 bf16x8 __attribute__((ext_vector_type(8)));
typedef float f32x4 __attribute__((ext_vector_type(4)));
typedef unsigned short u16;
typedef u16 u16x8 __attribute__((ext_vector_type(8)));

__device__ inline u16 f2bf(float f) {
  union { float f; unsigned u; } v; v.f = f;
  unsigned u = v.u;
  u += 0x7fff + ((u >> 16) & 1);  // RNE
  return (u16)(u >> 16);
}

#define GLL(gp, lp)                                                            \
  __builtin_amdgcn_global_load_lds(                                            \
      (const __attribute__((address_space(1))) void*)(gp),                     \
      (__attribute__((address_space(3))) void*)(lp), 16, 0, 0)

#define SBAR __builtin_amdgcn_sched_barrier(0)

// ---------------- kernel 1: prep weights ----------------
// wp[o][0:1024]=bf16(W_base), wp[o][1024+e*16+r]=bf16(Bs[e,o,r]); ap=bf16(As flat).
__global__ __launch_bounds__(256) void prep_w(const float* __restrict__ Wb,
                                              const float* __restrict__ Bs,
                                              const float* __restrict__ As,
                                              u16* __restrict__ wp,
                                              u16* __restrict__ ap) {
  int idx = blockIdx.x * 256 + threadIdx.x;
  if (idx < O_ * KK) {
    int o = idx / KK;
    int k = idx - o * KK;
    float v;
    if (k < C_) {
      v = Wb[o * C_ + k];
    } else {
      int j = k - C_;
      v = Bs[((j >> 4) * O_ + o) * R_ + (j & 15)];
    }
    wp[idx] = f2bf(v);
  } else {
    int a = idx - O_ * KK;  // 131,072 elements of As
    ap[a] = f2bf(As[a]);
  }
}

// ---------------- kernel 2a: streaming convert ----------------
// x fp32 (24000x1024) -> xp bf16 cols 0:1024 (row stride 1152). Pure
// memory-roofline: 98 MB read + 47 MB write, no barriers, no LDS.
__global__ __launch_bounds__(256) void cvt(const float* __restrict__ x,
                                           u16* __restrict__ xp) {
  const int t0 = blockIdx.x * 256 + threadIdx.x;  // 0..511999
#pragma unroll
  for (int u = 0; u < 6; ++u) {
    const int chunk = u * 512000 + t0;            // 0..3,071,999
    const int row = chunk >> 7;                   // 0..23999
    const int cc = (chunk & 127) * 8;             // 0..1016
    const float4 v0 = *(const float4*)&x[(size_t)row * C_ + cc];
    const float4 v1 = *(const float4*)&x[(size_t)row * C_ + cc + 4];
    u16x8 o;
    o[0] = f2bf(v0.x); o[1] = f2bf(v0.y); o[2] = f2bf(v0.z); o[3] = f2bf(v0.w);
    o[4] = f2bf(v1.x); o[5] = f2bf(v1.y); o[6] = f2bf(v1.z); o[7] = f2bf(v1.w);
    *(u16x8*)&xp[(size_t)row * KK + cc] = o;
  }
}

// ---------------- kernel 2b: LoRA h-GEMM + gate ----------------
// hg[row, e*16+r] = SCALING * w[b,e] * (x_bf16 @ As^T)  -> xp cols 1024:1152.
// M=24000 (375 x 64-row tiles), N=128, K=1024, BK=64, XOR-8 conflict-free.
__global__ __launch_bounds__(256) void h_gemm(const u16* __restrict__ xp,
                                              const u16* __restrict__ ab,
                                              const float* __restrict__ w,
                                              u16* __restrict__ xpo) {
  const int mt = blockIdx.x;  // 0..374 (exact: 375*64 = 24000)
  const int tid = threadIdx.x, lane = tid & 63, wv = tid >> 6;
  const int wrow = wv & 1, wcol = wv >> 1, l15 = lane & 15, quad = lane >> 4;
  const int s7 = l15 & 7;

  __shared__ u16 lA[64 * 64];    // 8 KB
  __shared__ u16 lB[128 * 64];   // 16 KB

  const u16* gA = xp + (size_t)mt * 64 * KK;

  f32x4 acc[2][4];
#pragma unroll
  for (int i = 0; i < 2; ++i)
#pragma unroll
    for (int j = 0; j < 4; ++j) acc[i][j] = (f32x4){0.f, 0.f, 0.f, 0.f};

  int arow[2], ako[2], brow[4], bko[4];
#pragma unroll
  for (int c = 0; c < 2; ++c) {
    int idx = c * 256 + tid;            // 0..511: row=idx>>3 (0..63)
    arow[c] = idx >> 3;
    ako[c] = (((idx & 7) ^ (arow[c] & 7)) << 3);
  }
#pragma unroll
  for (int c = 0; c < 4; ++c) {
    int idx = c * 256 + tid;            // 0..1023: row=idx>>3 (0..127)
    brow[c] = idx >> 3;
    bko[c] = (((idx & 7) ^ (brow[c] & 7)) << 3);
  }

  for (int kt = 0; kt < C_ / 64; ++kt) {  // 16 iterations
    const int k0 = kt * 64;
#pragma unroll
    for (int c = 0; c < 2; ++c)
      GLL(gA + (size_t)arow[c] * KK + k0 + ako[c], &lA[(c * 256 + tid) * 8]);
#pragma unroll
    for (int c = 0; c < 4; ++c)
      GLL(ab + brow[c] * C_ + k0 + bko[c], &lB[(c * 256 + tid) * 8]);
    __syncthreads();
#pragma unroll
    for (int kk = 0; kk < 2; ++kk) {
      const int ko = (((kk * 4 + quad) ^ s7) << 3);
      bf16x8 af[2], bfr[4];
#pragma unroll
      for (int i = 0; i < 2; ++i)
        af[i] = *(const bf16x8*)&lA[(wrow * 32 + i * 16 + l15) * 64 + ko];
#pragma unroll
      for (int j = 0; j < 4; ++j)
        bfr[j] = *(const bf16x8*)&lB[(wcol * 64 + j * 16 + l15) * 64 + ko];
#pragma unroll
      for (int i = 0; i < 2; ++i)
#pragma unroll
        for (int j = 0; j < 4; ++j)
          acc[i][j] = __builtin_amdgcn_mfma_f32_16x16x32_bf16(af[i], bfr[j], acc[i][j], 0, 0, 0);
    }
    __syncthreads();
  }

  // epilogue: col -> expert e = wcol*4+j (lane-uniform), rank r = l15
#pragma unroll
  for (int j = 0; j < 4; ++j) {
    const int col = wcol * 64 + j * 16 + l15;
    const int e = wcol * 4 + j;
#pragma unroll
    for (int i = 0; i < 2; ++i) {
#pragma unroll
      for (int rr = 0; rr < 4; ++rr) {
        const int row = mt * 64 + wrow * 32 + i * 16 + quad * 4 + rr;
        const int b = row / T_;
        xpo[(size_t)row * KK + C_ + col] = f2bf(acc[i][j][rr] * (SCALING * w[b * E_ + e]));
      }
    }
  }
}

// ---------------- kernel 3: main GEMM (3-buffer, 1 barrier/tile) ----------------
// out[row][o] = X'[row,:] . W'[o,:] + b_base[o];  M=24000 K=1152 N=1024.
// BM=128 BN=256 BK=64; 512 thr = 8 waves (2M x 4N), wave out 64x64
// (acc[4][4], 16 ds_read -> 32 MFMA per tile). LDS 3 x (8+16) KB buffers.
// Tile t reads buf[t%3], stages t+2 into buf[(t+2)%3] (= buffer read at t-1;
// safe past t's entry barrier since every wave drained lgkm(0) before it).
// Per tile: vmcnt(6) [t landed, t+1 flying] -> BARRIER -> 6 GLL (t+2) ->
// reads {af0,b01 | af1 | b23} pinned -> lgkm(8): q0 (8 MFMA) -> lgkm(4): q2
// (8) -> lgkm(0): q1+q3 (16). One barrier/tile (18 total vs 36).
// mt=187 staging over-reads rows 24000..24063 -> allocated W'/As region,
// stores row-masked. XCD map bijective (752 = 8*94), nt fastest -> A-panel
// (294 KB/mt) L2-hit across its 4 nt.
__global__ __launch_bounds__(512, 2) void main_gemm(const u16* __restrict__ xp,
                                                    const u16* __restrict__ wp,
                                                    const float* __restrict__ bb,
                                                    float* __restrict__ out) {
  const int id = blockIdx.x;                 // 0..751
  const int g = (id & 7) * 94 + (id >> 3);   // XCD-chunked tile index
  const int mt = g >> 2;                     // 0..187
  const int nt = g & 3;                      // 0..3
  const int tid = threadIdx.x, lane = tid & 63, wv = tid >> 6;  // 8 waves
  const int wm = wv >> 2, wn = wv & 3, l15 = lane & 15, quad = lane >> 4;
  const int s7 = l15 & 7;
  const int ko0 = (quad ^ s7) << 3;          // ks=0 logical chunk = quad
  const int ko1 = ((4 + quad) ^ s7) << 3;    // ks=1 logical chunk = 4+quad

  __shared__ u16 lA[3][128 * 64];  // 3 x 16 KB
  __shared__ u16 lB[3][256 * 64];  // 3 x 32 KB   (total 144 KB)

  const u16* gA = xp + (size_t)mt * 128 * KK;
  const u16* gB = wp + (size_t)nt * 256 * KK;

  f32x4 acc[4][4];
#pragma unroll
  for (int i = 0; i < 4; ++i)
#pragma unroll
    for (int j = 0; j < 4; ++j) acc[i][j] = (f32x4){0.f, 0.f, 0.f, 0.f};

  // staging: A 2 GLL rounds (1024 chunks), B 4 rounds (2048); XOR-8 swizzle:
  // phys chunk p=idx&7 of row idx>>3 holds logical chunk p^(row&7).
  const u16* pA[2];
  const u16* pB[4];
  int dA[2], dB[4];
#pragma unroll
  for (int c = 0; c < 2; ++c) {
    int idx = c * 512 + tid;          // row = idx>>3 (0..127)
    int row = idx >> 3;
    pA[c] = gA + (size_t)row * KK + (((idx & 7) ^ (row & 7)) << 3);
    dA[c] = idx * 8;
  }
#pragma unroll
  for (int c = 0; c < 4; ++c) {
    int idx = c * 512 + tid;          // row = idx>>3 (0..255)
    int row = idx >> 3;
    pB[c] = gB + (size_t)row * KK + (((idx & 7) ^ (row & 7)) << 3);
    dB[c] = idx * 8;
  }

#define ROWA(i) ((wm * 64 + (i) * 16 + l15) * 64)
#define ROWB(j) ((wn * 64 + (j) * 16 + l15) * 64)

  // prologue: tile0 -> buf0, tile1 -> buf1 (12 GLL outstanding)
#pragma unroll
  for (int c = 0; c < 2; ++c) GLL(pA[c], &lA[0][dA[c]]);
#pragma unroll
  for (int c = 0; c < 4; ++c) GLL(pB[c], &lB[0][dB[c]]);
#pragma unroll
  for (int c = 0; c < 2; ++c) GLL(pA[c] + 64, &lA[1][dA[c]]);
#pragma unroll
  for (int c = 0; c < 4; ++c) GLL(pB[c] + 64, &lB[1][dB[c]]);

  // BODY(T, CUR, N2): tile T reads buf[CUR]=T%3, stages T+2 into buf[N2]=(T+2)%3.
#define TILE_BODY(T, CUR, N2)                                                  \
  {                                                                            \
    const int t_ = (T);                                                        \
    if (t_ < NKT - 1) {                                                        \
      asm volatile("s_waitcnt vmcnt(6)" ::: "memory");                         \
    } else {                                                                   \
      asm volatile("s_waitcnt vmcnt(0)" ::: "memory");                         \
    }                                                                          \
    SBAR;                                                                      \
    __builtin_amdgcn_s_barrier(); /* tile T visible; buf[N2] free */           \
    SBAR;                                                                      \
    if (t_ + 2 < NKT) {                                                        \
      const int k2 = (t_ + 2) * 64;                                            \
      _Pragma("unroll")                                                        \
      for (int c = 0; c < 2; ++c) GLL(pA[c] + k2, &lA[N2][dA[c]]);             \
      _Pragma("unroll")                                                        \
      for (int c = 0; c < 4; ++c) GLL(pB[c] + k2, &lB[N2][dB[c]]);             \
    }                                                                          \
    SBAR;                                                                      \
    bf16x8 af[4][2], bfr[4][2];                                                \
    /* group 1: af0 (i=0,1) + b01 (j=0,1): 8 reads */                          \
    _Pragma("unroll")                                                          \
    for (int i = 0; i < 2; ++i) {                                              \
      af[i][0] = *(const bf16x8*)&lA[CUR][ROWA(i) + ko0];                      \
      af[i][1] = *(const bf16x8*)&lA[CUR][ROWA(i) + ko1];                      \
    }                                                                          \
    _Pragma("unroll")                                                          \
    for (int j = 0; j < 2; ++j) {                                              \
      bfr[j][0] = *(const bf16x8*)&lB[CUR][ROWB(j) + ko0];                     \
      bfr[j][1] = *(const bf16x8*)&lB[CUR][ROWB(j) + ko1];                     \
    }                                                                          \
    SBAR;                                                                      \
    /* group 2: af1 (i=2,3): 4 reads */                                        \
    _Pragma("unroll")                                                          \
    for (int i = 2; i < 4; ++i) {                                              \
      af[i][0] = *(const bf16x8*)&lA[CUR][ROWA(i) + ko0];                      \
      af[i][1] = *(const bf16x8*)&lA[CUR][ROWA(i) + ko1];                      \
    }                                                                          \
    SBAR;                                                                      \
    /* group 3: b23 (j=2,3): 4 reads */                                        \
    _Pragma("unroll")                                                          \
    for (int j = 2; j < 4; ++j) {                                              \
      bfr[j][0] = *(const bf16x8*)&lB[CUR][ROWB(j) + ko0];                     \
      bfr[j][1] = *(const bf16x8*)&lB[CUR][ROWB(j) + ko1];                     \
    }                                                                          \
    asm volatile("s_waitcnt lgkmcnt(8)" ::: "memory"); /* g1 done */           \
    SBAR;                                                                      \
    __builtin_amdgcn_s_setprio(1);                                             \
    _Pragma("unroll")                                                          \
    for (int ks = 0; ks < 2; ++ks)                                             \
      _Pragma("unroll")                                                        \
      for (int i = 0; i < 2; ++i)                                              \
        _Pragma("unroll")                                                      \
        for (int j = 0; j < 2; ++j)                                            \
          acc[i][j] = __builtin_amdgcn_mfma_f32_16x16x32_bf16(                 \
              af[i][ks], bfr[j][ks], acc[i][j], 0, 0, 0);                      \
    __builtin_amdgcn_s_setprio(0);                                             \
    asm volatile("s_waitcnt lgkmcnt(4)" ::: "memory"); /* af1 done */          \
    SBAR;                                                                      \
    __builtin_amdgcn_s_setprio(1);                                             \
    _Pragma("unroll")                                                          \
    for (int ks = 0; ks < 2; ++ks)                                             \
      _Pragma("unroll")                                                        \
      for (int i = 2; i < 4; ++i)                                              \
        _Pragma("unroll")                                                      \
        for (int j = 0; j < 2; ++j)                                            \
          acc[i][j] = __builtin_amdgcn_mfma_f32_16x16x32_bf16(                 \
              af[i][ks], bfr[j][ks], acc[i][j], 0, 0, 0);                      \
    __builtin_amdgcn_s_setprio(0);                                             \
    asm volatile("s_waitcnt lgkmcnt(0)" ::: "memory"); /* b23 done */          \
    SBAR;                                                                      \
    __builtin_amdgcn_s_setprio(1);                                             \
    _Pragma("unroll")                                                          \
    for (int ks = 0; ks < 2; ++ks)                                             \
      _Pragma("unroll")                                                        \
      for (int i = 0; i < 4; ++i)                                              \
        _Pragma("unroll")                                                      \
        for (int j = 2; j < 4; ++j)                                            \
          acc[i][j] = __builtin_amdgcn_mfma_f32_16x16x32_bf16(                 \
              af[i][ks], bfr[j][ks], acc[i][j], 0, 0, 0);                      \
    __builtin_amdgcn_s_setprio(0);                                             \
  }

  for (int tt = 0; tt < 6; ++tt) {
    TILE_BODY(3 * tt + 0, 0, 2)
    TILE_BODY(3 * tt + 1, 1, 0)
    TILE_BODY(3 * tt + 2, 2, 1)
  }
#undef TILE_BODY
#undef ROWA
#undef ROWB

#pragma unroll
  for (int j = 0; j < 4; ++j) {
    const int col = nt * 256 + wn * 64 + j * 16 + l15;
    const float bias = bb[col];
#pragma unroll
    for (int i = 0; i < 4; ++i) {
#pragma unroll
      for (int rr = 0; rr < 4; ++rr) {
        const int row = mt * 128 + wm * 64 + i * 16 + quad * 4 + rr;
        if (row < BT) out[(size_t)row * O_ + col] = acc[i][j][rr] + bias;
      }
    }
  }
}

extern "C" void kernel_launch(void* const* d_in, const int* in_sizes, int n_in,
                              void* d_out, int out_size, void* d_ws, size_t ws_size,
                              hipStream_t stream) {
  const float* x = (const float*)d_in[0];    // (16,1500,1024)
  const float* w = (const float*)d_in[1];    // (16,8)
  const float* Wb = (const float*)d_in[2];   // (1024,1024)
  const float* bb = (const float*)d_in[3];   // (1024,)
  const float* As = (const float*)d_in[4];   // (8,16,1024)
  const float* Bs = (const float*)d_in[5];   // (8,1024,16)
  float* out = (float*)d_out;                // (16,1500,1024) fp32

  // ws: X' (24000x1152 u16, 55.30 MB) | W' (1024x1152 u16, 2.36 MB) | Asb (128x1024 u16, 0.26 MB)
  // main_gemm mt=187 staging over-reads rows 24000..24063 -> land in W' region (allocated, masked).
  u16* xp = (u16*)d_ws;
  u16* wp = xp + (size_t)BT * KK;
  u16* ap = wp + (size_t)O_ * KK;

  prep_w<<<(O_ * KK + ER * C_) / 256, 256, 0, stream>>>(Wb, Bs, As, wp, ap);
  cvt<<<2000, 256, 0, stream>>>(x, xp);
  h_gemm<<<375, 256, 0, stream>>>(xp, ap, w, xp);
  main_gemm<<<752, 512, 0, stream>>>(xp, wp, bb, out);
}